// Round 5
// baseline (848.934 us; speedup 1.0000x reference)
//
#include <hip/hip_runtime.h>

// AutoregressiveForecaster R5: role-split wave pairs, 16 waves/CU, fused gates.
// 2-layer LSTM(H=64) + MLP head, 20 autoregressive steps, 24-window, B=8192.
//
//  - 512 blocks x 512 threads (8 waves). Block owns ONE 16-batch M-tile.
//  - Wave pair (k, k+4), k=0..3, shares unit-quarter k (units [16k,16k+16)):
//      role 0 (wave k):   gates i,g -> fused ig product -> LDS (f32 float4)
//      role 1 (wave k+4): gates f,o -> c-state, h = o*tanh(c) -> h LDS (f16)
//  - Fused transcendentals: ig = (1-y)*rcp((1+x)(1+y)), h = (1-z)*rcp(po(1+z))
//    -> 8 trans per (batch,unit,layer) instead of 10, 3 rcp instead of 5.
//  - Pipelined L1(t) + L0(t+1) per iteration (as R4), 2 barriers/iteration.
//  - Weights pre-scaled by log2(e) (2*log2(e) for g-gate). 12 uint4 weight
//    frags per wave -> ~120 VGPR -> 16 waves/CU (2 blocks/CU, 4 waves/SIMD).

typedef _Float16 f16x8 __attribute__((ext_vector_type(8)));
typedef float f32x4 __attribute__((ext_vector_type(4)));

#define NBLK 512
#define NTHR 512
#define SRB  160   // h row stride bytes (80 f16)

__device__ __forceinline__ float rcp_(float x) { return __builtin_amdgcn_rcpf(x); }
__device__ __forceinline__ float exp2_(float x) { return __builtin_amdgcn_exp2f(x); }
__device__ __forceinline__ f32x4 mfma16(uint4 a, uint4 b, f32x4 c) {
  return __builtin_amdgcn_mfma_f32_16x16x32_f16(
      __builtin_bit_cast(f16x8, a), __builtin_bit_cast(f16x8, b), c, 0, 0, 0);
}
__device__ __forceinline__ uint4 pack8s(const float* p, float s) {
  union { uint4 u; _Float16 h[8]; } r;
  #pragma unroll
  for (int i = 0; i < 8; ++i) r.h[i] = (_Float16)(p[i] * s);
  return r.u;
}

__global__ __launch_bounds__(NTHR, 4) void lstm_forecast(
    const float* __restrict__ x,
    const float* __restrict__ Wih0, const float* __restrict__ Whh0,
    const float* __restrict__ bih0, const float* __restrict__ bhh0,
    const float* __restrict__ Wih1, const float* __restrict__ Whh1,
    const float* __restrict__ bih1, const float* __restrict__ bhh1,
    const float* __restrict__ W1,   const float* __restrict__ b1,
    const float* __restrict__ W2,   const float* __restrict__ b2,
    const float* __restrict__ damping, const int* __restrict__ stepsPtr,
    float* __restrict__ out)
{
  __shared__ __align__(16) _Float16 h1s[2][16 * 80];
  __shared__ __align__(16) _Float16 h2s[2][16 * 80];
  __shared__ __align__(16) float igx[2][4][16][16];  // [layer][quarter][unit][batch]
  __shared__ __align__(16) float win[24 * 16];
  __shared__ __align__(16) float pcon[8][64];        // [0..3]=bias0*sc, [4..7]=wih0*sc
  __shared__ float pm[2][16];

  const int tid  = threadIdx.x;
  const int wave = tid >> 6;
  const int lane = tid & 63;
  const int cc   = lane & 15;
  const int hi   = lane >> 4;
  const int role = wave >> 2;   // 0: i,g producer; 1: f,o + state owner
  const int k    = wave & 3;    // unit-quarter
  const int b0g  = blockIdx.x * 16;
  const float L2E = 1.44269504089f;

  // ---- weight B-fragments (2 gate-slots per wave: gt = u*2 + role) ----
  uint4 wB0[2][2], wB1[2][2], wB2[2][2];
  float bias0u[2], wih0u[2];
  f32x4 bi1[2];
  #pragma unroll
  for (int u = 0; u < 2; ++u) {
    int gt = u * 2 + role;                 // role0: 0(i),2(g); role1: 1(f),3(o)
    float sc = (gt == 2) ? 2.0f * L2E : L2E;
    int row = gt * 64 + k * 16 + cc;
    #pragma unroll
    for (int f = 0; f < 2; ++f) {
      int col = f * 32 + hi * 8;
      wB0[u][f] = pack8s(Whh0 + row * 64 + col, sc);
      wB1[u][f] = pack8s(Wih1 + row * 64 + col, sc);
      wB2[u][f] = pack8s(Whh1 + row * 64 + col, sc);
    }
    bias0u[u] = (bih0[row] + bhh0[row]) * sc;
    wih0u[u]  = Wih0[row] * sc;
    float bc  = (bih1[row] + bhh1[row]) * sc;
    #pragma unroll
    for (int r = 0; r < 4; ++r) bi1[u][r] = bc;
  }
  // MLP frags: only waves 0,1 (role0, k<2)
  uint4 wM[2] = {};
  float w2v = 0.0f, b1vv = 0.0f;
  if (role == 0 && k < 2) {
    int row = k * 16 + cc;
    wM[0] = pack8s(W1 + row * 64 + hi * 8, 1.0f);
    wM[1] = pack8s(W1 + row * 64 + 32 + hi * 8, 1.0f);
    w2v  = W2[row];
    b1vv = b1[row];
  }
  const float alpha  = rcp_(1.0f + exp2_(-L2E * damping[0]));
  const int   nsteps = stepsPtr[0];
  const float b2v    = b2[0];

  // prologue constants into LDS: pcon[gt] = (bih0+bhh0)*sc, pcon[4+gt] = Wih0*sc
  for (int e = tid; e < 256; e += NTHR) {
    int gt = e >> 6, idx = e & 63;
    float sc = (gt == 2) ? 2.0f * L2E : L2E;
    int row = gt * 64 + idx;
    pcon[gt][idx]     = (bih0[row] + bhh0[row]) * sc;
    pcon[4 + gt][idx] = Wih0[row] * sc;
  }
  // window init: win[t*16+b] = x[(b0g+b)*24 + t]
  for (int e = tid; e < 384; e += NTHR) {
    int b = e & 15, t = e >> 4;
    win[t * 16 + b] = x[(b0g + b) * 24 + t];
  }
  __syncthreads();

  char* h1c0 = (char*)h1s[0];
  char* h1c1 = (char*)h1s[1];
  char* h2c0 = (char*)h2s[0];
  char* h2c1 = (char*)h2s[1];

  float prevp = 0.0f;

  for (int s = 0; s < nsteps; ++s) {
    float c1[4] = {0, 0, 0, 0}, c2s[4] = {0, 0, 0, 0};

    // ---- prologue: role1 computes full L0(0) elementwise (h1(-1)=0) ----
    if (role == 1) {
      float pb0[4], pw0[4];
      #pragma unroll
      for (int gt = 0; gt < 4; ++gt) {
        pb0[gt] = pcon[gt][k * 16 + cc];
        pw0[gt] = pcon[4 + gt][k * 16 + cc];
      }
      float4 xw = *(const float4*)&win[(s % 24) * 16 + hi * 4];
      float xa[4] = {xw.x, xw.y, xw.z, xw.w};
      #pragma unroll
      for (int r = 0; r < 4; ++r) {
        float ai = fmaf(xa[r], pw0[0], pb0[0]);
        float af = fmaf(xa[r], pw0[1], pb0[1]);
        float ag = fmaf(xa[r], pw0[2], pb0[2]);
        float ao = fmaf(xa[r], pw0[3], pb0[3]);
        float xx = exp2_(-ai), yy = exp2_(-ag);
        float ig = (1.0f - yy) * rcp_((1.0f + xx) * (1.0f + yy));
        (void)af;  // f*c0 = 0
        c1[r] = ig;
        float xo = exp2_(-ao);
        float z  = exp2_(-2.88539008178f * ig);
        float hv = (1.0f - z) * rcp_((1.0f + xo) * (1.0f + z));
        *(_Float16*)(h1c0 + (hi * 4 + r) * SRB + (k * 16 + cc) * 2) = (_Float16)hv;
      }
    }
    __syncthreads();
    uint4 a1lo = *(uint4*)(h1c0 + cc * SRB + hi * 16);
    uint4 a1hi = *(uint4*)(h1c0 + cc * SRB + hi * 16 + 64);
    uint4 a2lo = make_uint4(0, 0, 0, 0), a2hi = make_uint4(0, 0, 0, 0);

    // ---- main pipelined loop: iter t computes L1(t) and L0(t+1) ----
    for (int t = 0; t < 23; ++t) {
      int pb = (t + 1) & 1;
      int ph = s + t + 1; if (ph >= 24) ph -= 24;
      float4 xw = *(const float4*)&win[ph * 16 + hi * 4];
      float xa[4] = {xw.x, xw.y, xw.z, xw.w};

      f32x4 acc1[2], acc0[2];
      #pragma unroll
      for (int u = 0; u < 2; ++u) {
        f32x4 tv = mfma16(a1lo, wB1[u][0], bi1[u]);
        tv = mfma16(a1hi, wB1[u][1], tv);
        tv = mfma16(a2lo, wB2[u][0], tv);
        acc1[u] = mfma16(a2hi, wB2[u][1], tv);
      }
      #pragma unroll
      for (int u = 0; u < 2; ++u) {
        f32x4 ai;
        #pragma unroll
        for (int r = 0; r < 4; ++r) ai[r] = fmaf(xa[r], wih0u[u], bias0u[u]);
        f32x4 tv = mfma16(a1lo, wB0[u][0], ai);
        acc0[u] = mfma16(a1hi, wB0[u][1], tv);
      }

      float fh1[4], po1[4], fh0[4], po0[4];
      if (role == 0) {
        // fused ig = sigm(i)*tanh(g), both layers; write to exchange buffer
        float4 g1, g0;
        float ig1[4], ig0[4];
        #pragma unroll
        for (int r = 0; r < 4; ++r) {
          float xx = exp2_(-acc1[0][r]), yy = exp2_(-acc1[1][r]);
          ig1[r] = (1.0f - yy) * rcp_((1.0f + xx) * (1.0f + yy));
          float x0 = exp2_(-acc0[0][r]), y0 = exp2_(-acc0[1][r]);
          ig0[r] = (1.0f - y0) * rcp_((1.0f + x0) * (1.0f + y0));
        }
        g1.x = ig1[0]; g1.y = ig1[1]; g1.z = ig1[2]; g1.w = ig1[3];
        g0.x = ig0[0]; g0.y = ig0[1]; g0.z = ig0[2]; g0.w = ig0[3];
        *(float4*)&igx[1][k][cc][hi * 4] = g1;
        *(float4*)&igx[0][k][cc][hi * 4] = g0;
      } else {
        #pragma unroll
        for (int r = 0; r < 4; ++r) {
          fh1[r] = rcp_(1.0f + exp2_(-acc1[0][r]));
          po1[r] = 1.0f + exp2_(-acc1[1][r]);
          fh0[r] = rcp_(1.0f + exp2_(-acc0[0][r]));
          po0[r] = 1.0f + exp2_(-acc0[1][r]);
        }
      }
      __syncthreads();

      if (role == 1) {
        float4 g1 = *(float4*)&igx[1][k][cc][hi * 4];
        float4 g0 = *(float4*)&igx[0][k][cc][hi * 4];
        float gg1[4] = {g1.x, g1.y, g1.z, g1.w};
        float gg0[4] = {g0.x, g0.y, g0.z, g0.w};
        char* h2d = (pb ? h2c1 : h2c0);
        char* h1d = (pb ? h1c1 : h1c0);
        #pragma unroll
        for (int r = 0; r < 4; ++r) {
          c2s[r] = fmaf(fh1[r], c2s[r], gg1[r]);
          float z = exp2_(-2.88539008178f * c2s[r]);
          float hv = (1.0f - z) * rcp_(po1[r] * (1.0f + z));
          *(_Float16*)(h2d + (hi * 4 + r) * SRB + (k * 16 + cc) * 2) = (_Float16)hv;
        }
        #pragma unroll
        for (int r = 0; r < 4; ++r) {
          c1[r] = fmaf(fh0[r], c1[r], gg0[r]);
          float z = exp2_(-2.88539008178f * c1[r]);
          float hv = (1.0f - z) * rcp_(po0[r] * (1.0f + z));
          *(_Float16*)(h1d + (hi * 4 + r) * SRB + (k * 16 + cc) * 2) = (_Float16)hv;
        }
      }
      __syncthreads();

      char* h1r = (pb ? h1c1 : h1c0);
      char* h2r = (pb ? h2c1 : h2c0);
      a1lo = *(uint4*)(h1r + cc * SRB + hi * 16);
      a1hi = *(uint4*)(h1r + cc * SRB + hi * 16 + 64);
      a2lo = *(uint4*)(h2r + cc * SRB + hi * 16);
      a2hi = *(uint4*)(h2r + cc * SRB + hi * 16 + 64);
    } // t

    // ---- epilogue: L1(23) only ----
    {
      f32x4 acc1[2];
      #pragma unroll
      for (int u = 0; u < 2; ++u) {
        f32x4 tv = mfma16(a1lo, wB1[u][0], bi1[u]);
        tv = mfma16(a1hi, wB1[u][1], tv);
        tv = mfma16(a2lo, wB2[u][0], tv);
        acc1[u] = mfma16(a2hi, wB2[u][1], tv);
      }
      float fh1[4], po1[4];
      if (role == 0) {
        float4 g1;
        float ig1[4];
        #pragma unroll
        for (int r = 0; r < 4; ++r) {
          float xx = exp2_(-acc1[0][r]), yy = exp2_(-acc1[1][r]);
          ig1[r] = (1.0f - yy) * rcp_((1.0f + xx) * (1.0f + yy));
        }
        g1.x = ig1[0]; g1.y = ig1[1]; g1.z = ig1[2]; g1.w = ig1[3];
        *(float4*)&igx[1][k][cc][hi * 4] = g1;
      } else {
        #pragma unroll
        for (int r = 0; r < 4; ++r) {
          fh1[r] = rcp_(1.0f + exp2_(-acc1[0][r]));
          po1[r] = 1.0f + exp2_(-acc1[1][r]);
        }
      }
      __syncthreads();
      if (role == 1) {
        float4 g1 = *(float4*)&igx[1][k][cc][hi * 4];
        float gg1[4] = {g1.x, g1.y, g1.z, g1.w};
        #pragma unroll
        for (int r = 0; r < 4; ++r) {
          float cv = fmaf(fh1[r], c2s[r], gg1[r]);
          float z = exp2_(-2.88539008178f * cv);
          float hv = (1.0f - z) * rcp_(po1[r] * (1.0f + z));
          *(_Float16*)(h2c0 + (hi * 4 + r) * SRB + (k * 16 + cc) * 2) = (_Float16)hv;
        }
      }
      __syncthreads();
    }

    // ---- MLP head on h2(23): waves 0,1 ----
    if (role == 0 && k < 2) {
      uint4 hflo = *(uint4*)(h2c0 + cc * SRB + hi * 16);
      uint4 hfhi = *(uint4*)(h2c0 + cc * SRB + hi * 16 + 64);
      f32x4 am;
      #pragma unroll
      for (int r = 0; r < 4; ++r) am[r] = b1vv;
      am = mfma16(hflo, wM[0], am);
      am = mfma16(hfhi, wM[1], am);
      float yp[4];
      #pragma unroll
      for (int r = 0; r < 4; ++r) yp[r] = fmaxf(am[r], 0.0f) * w2v;
      #pragma unroll
      for (int mask = 1; mask <= 8; mask <<= 1) {
        #pragma unroll
        for (int r = 0; r < 4; ++r) yp[r] += __shfl_xor(yp[r], mask);
      }
      if (cc == 0) {
        #pragma unroll
        for (int r = 0; r < 4; ++r) pm[k][hi * 4 + r] = yp[r];
      }
    }
    __syncthreads();

    if (wave == 0 && lane < 16) {
      float y = pm[0][lane] + pm[1][lane] + b2v;
      float pd = (s == 0) ? y : fmaf(y, 1.0f - alpha, prevp * (alpha * 0.5f));
      prevp = pd;
      win[(s % 24) * 16 + lane] = pd;
      out[(long)(b0g + lane) * nsteps + s] = pd;
    }
    __syncthreads();
  } // s
}

extern "C" void kernel_launch(void* const* d_in, const int* in_sizes, int n_in,
                              void* d_out, int out_size, void* d_ws, size_t ws_size,
                              hipStream_t stream) {
  (void)in_sizes; (void)n_in; (void)out_size; (void)d_ws; (void)ws_size;
  lstm_forecast<<<NBLK, NTHR, 0, stream>>>(
      (const float*)d_in[0],
      (const float*)d_in[1],  (const float*)d_in[2],
      (const float*)d_in[3],  (const float*)d_in[4],
      (const float*)d_in[5],  (const float*)d_in[6],
      (const float*)d_in[7],  (const float*)d_in[8],
      (const float*)d_in[9],  (const float*)d_in[10],
      (const float*)d_in[11], (const float*)d_in[12],
      (const float*)d_in[13], (const int*)d_in[14],
      (float*)d_out);
}

// Round 6
// 700.278 us; speedup vs baseline: 1.2123x; 1.2123x over previous
//
#include <hip/hip_runtime.h>

// AutoregressiveForecaster R6: layer-split wave groups, uniform code, 1 barrier/iter.
// 2-layer LSTM(H=64) + MLP head, 20 autoregressive steps, 24-window, B=8192.
//
//  - 512 blocks x 512 threads (8 waves). Block owns ONE 16-batch M-tile.
//  - Waves 0-3 (G0): layer-0 worker for unit-quarter k=wave. Waves 4-7 (G1):
//    layer-1 worker for quarter k=wave-4. Iteration i: G0 does L0(t=i),
//    G1 does L1(t=i-1). 25 iters/step, ping-pong h buffers, 1 barrier/iter.
//  - UNIFORM code: every wave runs 4 gate-tiles x 4 chained MFMA + fused
//    elementwise. G0 packs slot-2/3 weights with scale 0 (contributes 0);
//    G1 packs x-weight 0. Only data differs per wave -> no divergence, no
//    union-of-branches register pressure (R5's spill cause).
//  - Fused gates: 8 trans/unit-step (5 exp2 + 3 rcp). Weights pre-scaled by
//    log2e (2x for g-gate). G1 iter-0 garbage suppressed via c-mask (h=0 follows).
//  - MLP weights in LDS (cold path) to keep hot-loop VGPR <= 128 (4 waves/SIMD).

typedef _Float16 f16x8 __attribute__((ext_vector_type(8)));
typedef float f32x4 __attribute__((ext_vector_type(4)));

#define NBLK 512
#define NTHR 512
#define SRB  160   // h row stride bytes (80 f16)

__device__ __forceinline__ float rcp_(float x) { return __builtin_amdgcn_rcpf(x); }
__device__ __forceinline__ float exp2_(float x) { return __builtin_amdgcn_exp2f(x); }
__device__ __forceinline__ f32x4 mfma16(uint4 a, uint4 b, f32x4 c) {
  return __builtin_amdgcn_mfma_f32_16x16x32_f16(
      __builtin_bit_cast(f16x8, a), __builtin_bit_cast(f16x8, b), c, 0, 0, 0);
}
__device__ __forceinline__ uint4 pack8s(const float* p, float s) {
  union { uint4 u; _Float16 h[8]; } r;
  #pragma unroll
  for (int i = 0; i < 8; ++i) r.h[i] = (_Float16)(p[i] * s);
  return r.u;
}

__global__ __launch_bounds__(NTHR, 4) void lstm_forecast(
    const float* __restrict__ x,
    const float* __restrict__ Wih0, const float* __restrict__ Whh0,
    const float* __restrict__ bih0, const float* __restrict__ bhh0,
    const float* __restrict__ Wih1, const float* __restrict__ Whh1,
    const float* __restrict__ bih1, const float* __restrict__ bhh1,
    const float* __restrict__ W1,   const float* __restrict__ b1,
    const float* __restrict__ W2,   const float* __restrict__ b2,
    const float* __restrict__ damping, const int* __restrict__ stepsPtr,
    float* __restrict__ out)
{
  __shared__ __align__(16) _Float16 h1s[2][1280];   // [parity][16 x 80]
  __shared__ __align__(16) _Float16 h2s[2][1280];
  __shared__ __align__(16) float    win[24 * 16];
  __shared__ __align__(16) uint4    wfm[4][64];     // MLP W1 frags
  __shared__ float w2s[32], b1s[32];
  __shared__ float pm[2][16];

  const int tid   = threadIdx.x;
  const int wave  = tid >> 6;
  const int lane  = tid & 63;
  const int cc    = lane & 15;
  const int hi    = lane >> 4;
  const int group = wave >> 2;       // 0: layer-0 worker, 1: layer-1 worker
  const int k     = wave & 3;        // unit quarter
  const int b0g   = blockIdx.x * 16;
  const float L2E = 1.44269504089f;

  // ---- weight B-fragments into VGPRs (uniform shape, group-dependent data) --
  const float* srcA = group ? Wih1 : Whh0;
  const float* srcB = group ? Whh1 : Whh0;     // G0: dummy, scaled by 0
  const float  sB   = group ? 1.0f : 0.0f;
  uint4 wF[4][4];
  float wxv[4], bxv[4];
  #pragma unroll
  for (int gt = 0; gt < 4; ++gt) {
    float sc = (gt == 2) ? 2.0f * L2E : L2E;
    int row = gt * 64 + k * 16 + cc;
    #pragma unroll
    for (int f = 0; f < 2; ++f) {
      int col = f * 32 + hi * 8;
      wF[gt][f]     = pack8s(srcA + row * 64 + col, sc);
      wF[gt][2 + f] = pack8s(srcB + row * 64 + col, sc * sB);
    }
    bxv[gt] = (group ? (bih1[row] + bhh1[row]) : (bih0[row] + bhh0[row])) * sc;
    wxv[gt] = group ? 0.0f : Wih0[row] * sc;
  }
  // MLP weights -> LDS (cold path; keeps hot-loop VGPR low)
  for (int e = tid; e < 256; e += NTHR) {
    int l = e & 63, f = (e >> 6) & 1, n = e >> 7;
    wfm[n * 2 + f][l] =
        pack8s(W1 + (n * 16 + (l & 15)) * 64 + f * 32 + (l >> 4) * 8, 1.0f);
  }
  if (tid < 32) { w2s[tid] = W2[tid]; b1s[tid] = b1[tid]; }
  // window init: win[t*16+b] = x[(b0g+b)*24 + t]
  for (int e = tid; e < 384; e += NTHR) {
    int b = e & 15, t = e >> 4;
    win[t * 16 + b] = x[(b0g + b) * 24 + t];
  }
  const float alpha  = rcp_(1.0f + exp2_(-L2E * damping[0]));
  const int   nsteps = stepsPtr[0];
  const float b2v    = b2[0];
  __syncthreads();

  const int offA = cc * SRB + hi * 16;      // A-frag byte offset
  float prevp = 0.0f;

#define ITER(P, WM)                                                            \
  do {                                                                         \
    const char* rb1 = (const char*)h1s[P];                                     \
    const char* rb2 = (const char*)h2s[P];                                     \
    uint4 a1lo = *(const uint4*)(rb1 + offA);                                  \
    uint4 a1hi = *(const uint4*)(rb1 + offA + 64);                             \
    uint4 a2lo = *(const uint4*)(rb2 + offA);                                  \
    uint4 a2hi = *(const uint4*)(rb2 + offA + 64);                             \
    float4 xw = *(const float4*)&win[ph * 16 + hi * 4];                        \
    f32x4 acc[4];                                                              \
    _Pragma("unroll")                                                          \
    for (int gt = 0; gt < 4; ++gt) {                                           \
      f32x4 ai;                                                                \
      ai[0] = fmaf(xw.x, wxv[gt], bxv[gt]);                                    \
      ai[1] = fmaf(xw.y, wxv[gt], bxv[gt]);                                    \
      ai[2] = fmaf(xw.z, wxv[gt], bxv[gt]);                                    \
      ai[3] = fmaf(xw.w, wxv[gt], bxv[gt]);                                    \
      f32x4 tv = mfma16(a1lo, wF[gt][0], ai);                                  \
      tv = mfma16(a1hi, wF[gt][1], tv);                                        \
      tv = mfma16(a2lo, wF[gt][2], tv);                                        \
      acc[gt] = mfma16(a2hi, wF[gt][3], tv);                                   \
    }                                                                          \
    char* dst = group ? (char*)h2s[P ^ 1] : (char*)h1s[P ^ 1];                 \
    _Pragma("unroll")                                                          \
    for (int r = 0; r < 4; ++r) {                                              \
      float xx = exp2_(-acc[0][r]);                                            \
      float xf = exp2_(-acc[1][r]);                                            \
      float yy = exp2_(-acc[2][r]);                                            \
      float xo = exp2_(-acc[3][r]);                                            \
      float ig = (1.0f - yy) * rcp_((1.0f + xx) * (1.0f + yy));                \
      float fh = rcp_(1.0f + xf);                                              \
      float cv = (WM) * fmaf(fh, cst[r], ig);                                  \
      cst[r] = cv;                                                             \
      float z  = exp2_(-2.88539008178f * cv);                                  \
      float hv = (1.0f - z) * rcp_((1.0f + xo) * (1.0f + z));                  \
      *(_Float16*)(dst + (hi * 4 + r) * SRB + (k * 16 + cc) * 2) =             \
          (_Float16)hv;                                                        \
    }                                                                          \
    __syncthreads();                                                           \
    ph = (ph >= 23) ? 0 : ph + 1;                                              \
  } while (0)

  #pragma unroll 1
  for (int s = 0; s < nsteps; ++s) {
    // zero parity-0 buffers (read at iter 0)
    {
      unsigned* z1 = (unsigned*)h1s[0];
      unsigned* z2 = (unsigned*)h2s[0];
      for (int e = tid; e < 640; e += NTHR) { z1[e] = 0; z2[e] = 0; }
    }
    __syncthreads();

    float cst[4] = {0, 0, 0, 0};
    int ph = s; while (ph >= 24) ph -= 24;

    const float wm0 = group ? 0.0f : 1.0f;   // suppress G1's t=-1 garbage
    ITER(0, wm0);
    #pragma unroll 1
    for (int ii = 0; ii < 12; ++ii) {
      ITER(1, 1.0f);
      ITER(0, 1.0f);
    }
    // after 25 iters: h2(23) sits in h2s[1]

    // ---- MLP head (waves 0,1) ----
    if (wave < 2) {
      uint4 hflo = *(const uint4*)((const char*)h2s[1] + offA);
      uint4 hfhi = *(const uint4*)((const char*)h2s[1] + offA + 64);
      uint4 m0 = wfm[wave * 2 + 0][lane];
      uint4 m1 = wfm[wave * 2 + 1][lane];
      float b1vv = b1s[wave * 16 + cc];
      float w2v  = w2s[wave * 16 + cc];
      f32x4 am;
      #pragma unroll
      for (int r = 0; r < 4; ++r) am[r] = b1vv;
      am = mfma16(hflo, m0, am);
      am = mfma16(hfhi, m1, am);
      float yp[4];
      #pragma unroll
      for (int r = 0; r < 4; ++r) yp[r] = fmaxf(am[r], 0.0f) * w2v;
      #pragma unroll
      for (int mask = 1; mask <= 8; mask <<= 1) {
        #pragma unroll
        for (int r = 0; r < 4; ++r) yp[r] += __shfl_xor(yp[r], mask);
      }
      if (cc == 0) {
        #pragma unroll
        for (int r = 0; r < 4; ++r) pm[wave][hi * 4 + r] = yp[r];
      }
    }
    __syncthreads();

    if (wave == 0 && lane < 16) {
      float y = pm[0][lane] + pm[1][lane] + b2v;
      float pd = (s == 0) ? y : fmaf(y, 1.0f - alpha, prevp * (alpha * 0.5f));
      prevp = pd;
      int slot = s; while (slot >= 24) slot -= 24;
      win[slot * 16 + lane] = pd;
      out[(long)(b0g + lane) * nsteps + s] = pd;
    }
    __syncthreads();
  } // s
#undef ITER
}

extern "C" void kernel_launch(void* const* d_in, const int* in_sizes, int n_in,
                              void* d_out, int out_size, void* d_ws, size_t ws_size,
                              hipStream_t stream) {
  (void)in_sizes; (void)n_in; (void)out_size; (void)d_ws; (void)ws_size;
  lstm_forecast<<<NBLK, NTHR, 0, stream>>>(
      (const float*)d_in[0],
      (const float*)d_in[1],  (const float*)d_in[2],
      (const float*)d_in[3],  (const float*)d_in[4],
      (const float*)d_in[5],  (const float*)d_in[6],
      (const float*)d_in[7],  (const float*)d_in[8],
      (const float*)d_in[9],  (const float*)d_in[10],
      (const float*)d_in[11], (const float*)d_in[12],
      (const float*)d_in[13], (const int*)d_in[14],
      (float*)d_out);
}